// Round 3
// baseline (744.101 us; speedup 1.0000x reference)
//
#include <hip/hip_runtime.h>

typedef __attribute__((ext_vector_type(8))) short short8;
typedef __attribute__((ext_vector_type(4))) short short4v;
typedef __attribute__((ext_vector_type(4))) float f32x4;

constexpr int NN = 100000;
constexpr int EE = 1600000;
constexpr int DD = 128;
constexpr int CC = 47;
constexpr int NB = 391;      // buckets of 256 dst nodes (dst>>8)
constexpr int BSLOT = 5120;  // padded bucket capacity
constexpr int SLICE = NN * 16;   // shorts per 16-col slice (sliced layout [8][NN][16])
constexpr int GB = 782;      // gemm grid (128 rows each)

// ---- workspace layout (bytes) ----
constexpr size_t OFF_XB   = 0;           // [8][NN][16] bf16 running x (slice-major)
constexpr size_t OFF_MB   = 25600000;    // [8][NN][16] bf16 mean agg (slice-major)
constexpr size_t OFF_HB   = 51200000;    // N*D bf16 pre-BN h (row-major)
constexpr size_t OFF_BIN  = 76800000;    // NB*BSLOT u32 binned packed edges
constexpr size_t OFF_CSR  = 84808192;    // E i32
constexpr size_t OFF_RP   = 91208192;    // N+1 i32 rowptr
constexpr size_t OFF_CUR  = 91608832;    // NB i32 bucket cursors/totals
constexpr size_t OFF_BASE = 91610880;    // NB i32 bucket bases
constexpr size_t OFF_W    = 91612928;    // 104448 bf16 frag-ordered weights
constexpr size_t OFF_ST   = 91821824;    // 256 f32 stats (sum, sumsq)
constexpr size_t OFF_PB   = 91822848;    // GB*256 f32 per-block stat partials

static __device__ __forceinline__ float bf2f(unsigned short u) {
    return __uint_as_float(((unsigned)u) << 16);
}
static __device__ __forceinline__ unsigned short f2bf(float f) {
    unsigned u = __float_as_uint(f);
    unsigned r = (u + 0x7fffu + ((u >> 16) & 1u)) >> 16;
    return (unsigned short)r;
}

// ---- prep: weights -> bf16, MFMA-fragment order ----
__global__ void k_convw(const float* __restrict__ wl1, const float* __restrict__ wr1,
                        const float* __restrict__ wl2, const float* __restrict__ wr2,
                        const float* __restrict__ wl3, const float* __restrict__ wr3,
                        const float* __restrict__ lw, unsigned short* __restrict__ dst) {
    int id = blockIdx.x * 256 + threadIdx.x;
    if (id < 98304) {
        int L = id >> 15;
        int r = id & 32767;
        int mat = r >> 14;
        int t = r & 16383;
        int j = t & 7, lane = (t >> 3) & 63, ct = (t >> 9) & 7, ks = t >> 12;
        int row = ct * 16 + (lane & 15);
        int col = ks * 32 + ((lane >> 4) << 3) + j;
        const float* src = (L == 0) ? (mat ? wr1 : wl1)
                         : (L == 1) ? (mat ? wr2 : wl2)
                                    : (mat ? wr3 : wl3);
        dst[id] = f2bf(src[row * 128 + col]);
    } else if (id < 98304 + 6144) {
        int t = id - 98304;
        int j = t & 7, lane = (t >> 3) & 63, m = t >> 9;
        int ct = m % 3, ks = m / 3;
        int row = ct * 16 + (lane & 15);
        int col = ks * 32 + ((lane >> 4) << 3) + j;
        dst[id] = (row < CC) ? f2bf(lw[row * 128 + col]) : (unsigned short)0;
    }
}

// ---- x (row-major f32) -> xb (slice-major bf16) ----
__global__ void k_convx(const float* __restrict__ x, unsigned short* __restrict__ xb) {
    int s = blockIdx.x / GB;
    int bi = blockIdx.x - s * GB;
    int off = bi * 2048 + threadIdx.x * 8;   // short offset within slice
    if (off >= SLICE) return;
    int node = off >> 4;
    int j0 = off & 15;                       // 0 or 8
    int col = s * 16 + j0;
    const float* src = x + (size_t)node * 128 + col;
    float4 v1 = *(const float4*)(src);
    float4 v2 = *(const float4*)(src + 4);
    short8 o = { (short)f2bf(v1.x), (short)f2bf(v1.y), (short)f2bf(v1.z), (short)f2bf(v1.w),
                 (short)f2bf(v2.x), (short)f2bf(v2.y), (short)f2bf(v2.z), (short)f2bf(v2.w) };
    *(short8*)(xb + (size_t)s * SLICE + off) = o;
}

// ---- pass A: bin edges by dst>>8 ----
__global__ __launch_bounds__(256) void k_bin(const int* __restrict__ ei,
                                             int* __restrict__ cur, int* __restrict__ bin) {
    __shared__ int cnt[NB];
    int t = threadIdx.x;
    for (int b = t; b < NB; b += 256) cnt[b] = 0;
    __syncthreads();
    int start = blockIdx.x * 3125;
    for (int i = t; i < 3125; i += 256) {
        int d = ei[EE + start + i];
        atomicAdd(&cnt[d >> 8], 1);
    }
    __syncthreads();
    int c[2], b0[2];
    #pragma unroll
    for (int k = 0; k < 2; ++k) {
        int b = t + k * 256;
        if (b < NB) { c[k] = cnt[b]; b0[k] = (c[k] > 0) ? atomicAdd(&cur[b], c[k]) : 0; }
    }
    __syncthreads();
    #pragma unroll
    for (int k = 0; k < 2; ++k) {
        int b = t + k * 256;
        if (b < NB) cnt[b] = b0[k];
    }
    __syncthreads();
    for (int i = t; i < 3125; i += 256) {
        int s = ei[start + i];
        int d = ei[EE + start + i];
        int b = d >> 8;
        int p = atomicAdd(&cnt[b], 1);
        if (p < BSLOT) bin[b * BSLOT + p] = (s << 8) | (d & 255);
    }
}

__global__ void k_base(const int* __restrict__ cur, int* __restrict__ base, int* __restrict__ rp) {
    __shared__ int sd[512];
    int t = threadIdx.x;
    int v0 = (t < NB) ? cur[t] : 0;
    sd[t] = v0;
    __syncthreads();
    for (int off = 1; off < 512; off <<= 1) {
        int v = (t >= off) ? sd[t - off] : 0;
        __syncthreads();
        sd[t] += v;
        __syncthreads();
    }
    if (t < NB) base[t] = sd[t] - v0;
    if (t == NB - 1) rp[NN] = sd[t];
}

__global__ __launch_bounds__(256) void k_build(const int* __restrict__ cur, const int* __restrict__ base,
                                               int* __restrict__ rp, const int* __restrict__ bin,
                                               int* __restrict__ csr) {
    __shared__ int lcnt[256], lsc[256], lrun[256];
    int b = blockIdx.x, t = threadIdx.x;
    int n0 = b << 8;
    int nodes = NN - n0; if (nodes > 256) nodes = 256;
    int tot = cur[b]; if (tot > BSLOT) tot = BSLOT;
    int bb = base[b];
    lcnt[t] = 0;
    __syncthreads();
    const int* bsrc = bin + b * BSLOT;
    for (int i = t; i < tot; i += 256) atomicAdd(&lcnt[bsrc[i] & 255], 1);
    __syncthreads();
    int c = lcnt[t];
    lsc[t] = c;
    __syncthreads();
    for (int off = 1; off < 256; off <<= 1) {
        int v = (t >= off) ? lsc[t - off] : 0;
        __syncthreads();
        lsc[t] += v;
        __syncthreads();
    }
    int excl = lsc[t] - c;
    if (t < nodes) rp[n0 + t] = bb + excl;
    lrun[t] = bb + excl;
    __syncthreads();
    for (int i = t; i < tot; i += 256) {
        int v = bsrc[i];
        int p = atomicAdd(&lrun[v & 255], 1);
        csr[p] = v >> 8;
    }
}

// ---- mean aggregation, col-sliced for per-XCD L2 residency ----
// block: slice = blockIdx%8 (XCD swizzle), 64 nodes per block (16/wave).
// lane owns (node, 4 cols); edges serial per lane; no shuffles.
__global__ __launch_bounds__(256) void k_agg(const int* __restrict__ rp, const int* __restrict__ csr,
                                             const unsigned short* __restrict__ xb,
                                             unsigned short* __restrict__ mb) {
    int s = blockIdx.x & 7;
    int cb = blockIdx.x >> 3;
    int wave = threadIdx.x >> 6, lane = threadIdx.x & 63;
    int nd = lane >> 2, sub = lane & 3;
    int node = cb * 64 + wave * 16 + nd;
    if (node >= NN) return;
    int s0 = rp[node], s1 = rp[node + 1];
    const unsigned short* xs = xb + (size_t)s * SLICE + (sub << 2);
    float a0 = 0.f, a1 = 0.f, a2 = 0.f, a3 = 0.f;
    for (int e = s0; e < s1; ++e) {
        int src = csr[e];
        short4v v = *(const short4v*)(xs + ((size_t)src << 4));
        a0 += bf2f((unsigned short)v[0]);
        a1 += bf2f((unsigned short)v[1]);
        a2 += bf2f((unsigned short)v[2]);
        a3 += bf2f((unsigned short)v[3]);
    }
    int deg = s1 - s0;
    float inv = 1.0f / (float)(deg > 1 ? deg : 1);
    short4v o = { (short)f2bf(a0 * inv), (short)f2bf(a1 * inv),
                  (short)f2bf(a2 * inv), (short)f2bf(a3 * inv) };
    *(short4v*)(mb + (size_t)s * SLICE + ((size_t)node << 4) + (sub << 2)) = o;
}

// ---- fused SAGE GEMM: h = x@Wl^T + bl + mean@Wr^T; per-block stat partials ----
__global__ __launch_bounds__(256, 4) void k_gemm(const unsigned short* __restrict__ xb,
                                                 const unsigned short* __restrict__ mb,
                                                 const unsigned short* __restrict__ wf,
                                                 const float* __restrict__ bias,
                                                 unsigned short* __restrict__ hb,
                                                 float* __restrict__ pbuf) {
    __shared__ unsigned short wsh[16384];   // 32 KB: one matrix at a time
    __shared__ float rbuf[1024];            // cross-wave stat reduce
    int tid = threadIdx.x;
    int wave = tid >> 6, lane = tid & 63, q = lane >> 4, l15 = lane & 15;
    int rowbase = blockIdx.x * 128 + wave * 32;

    f32x4 acc[2][8];
    #pragma unroll
    for (int ct = 0; ct < 8; ++ct) {
        float bv = bias[ct * 16 + l15];
        f32x4 t = {bv, bv, bv, bv};
        acc[0][ct] = t; acc[1][ct] = t;
    }

    #pragma unroll
    for (int mat = 0; mat < 2; ++mat) {
        const unsigned short* src = mat ? mb : xb;
        const int4* wsrc = (const int4*)(wf + (mat << 14));
        if (mat) __syncthreads();           // drain mat-0 LDS reads before overwrite
        #pragma unroll
        for (int i = 0; i < 8; ++i)
            ((int4*)wsh)[tid + i * 256] = wsrc[tid + i * 256];
        __syncthreads();
        #pragma unroll
        for (int ks = 0; ks < 4; ++ks) {
            int slice = ks * 2 + (q >> 1);
            const unsigned short* sp = src + (size_t)slice * SLICE + ((q & 1) << 3);
            short8 a[2];
            #pragma unroll
            for (int rt = 0; rt < 2; ++rt) {
                int row = rowbase + rt * 16 + l15;
                if (row < NN) a[rt] = *(const short8*)(sp + ((size_t)row << 4));
                else          a[rt] = short8{0,0,0,0,0,0,0,0};
            }
            #pragma unroll
            for (int ct = 0; ct < 8; ++ct) {
                short8 b = *(const short8*)(wsh + ((ks * 8 + ct) << 9) + (lane << 3));
                acc[0][ct] = __builtin_amdgcn_mfma_f32_16x16x32_bf16(a[0], b, acc[0][ct], 0, 0, 0);
                acc[1][ct] = __builtin_amdgcn_mfma_f32_16x16x32_bf16(a[1], b, acc[1][ct], 0, 0, 0);
            }
        }
    }

    // epilogue: bf16 store + per-block column stat partials (no global atomics)
    #pragma unroll
    for (int ct = 0; ct < 8; ++ct) {
        int colg = ct * 16 + l15;
        float sv = 0.f, qv = 0.f;
        #pragma unroll
        for (int rt = 0; rt < 2; ++rt) {
            #pragma unroll
            for (int r = 0; r < 4; ++r) {
                int row = rowbase + rt * 16 + (q << 2) + r;
                if (row < NN) {
                    float v = acc[rt][ct][r];
                    hb[(size_t)row * 128 + colg] = f2bf(v);
                    sv += v; qv += v * v;
                }
            }
        }
        sv += __shfl_xor(sv, 16); sv += __shfl_xor(sv, 32);
        qv += __shfl_xor(qv, 16); qv += __shfl_xor(qv, 32);
        if (q == 0) {
            rbuf[wave * 256 + colg] = sv;
            rbuf[wave * 256 + 128 + colg] = qv;
        }
    }
    __syncthreads();
    if (tid < 256) {
        float v = rbuf[tid] + rbuf[256 + tid] + rbuf[512 + tid] + rbuf[768 + tid];
        pbuf[(size_t)blockIdx.x * 256 + tid] = v;
    }
}

// ---- reduce stat partials: st[c]=sum, st[128+c]=sumsq ----
__global__ void k_stat2(const float* __restrict__ pbuf, float* __restrict__ st) {
    int b = blockIdx.x, t = threadIdx.x;   // 8 blocks x 256
    int r0 = b * 98;
    int r1 = r0 + 98; if (r1 > GB) r1 = GB;
    float s = 0.f;
    for (int r = r0; r < r1; ++r) s += pbuf[(size_t)r * 256 + t];
    atomicAdd(&st[t], s);
}

// ---- BatchNorm + ReLU + residual on sliced xb ----
__global__ void k_bn(const unsigned short* __restrict__ hb,
                     const float* __restrict__ stats, const float* __restrict__ gam,
                     const float* __restrict__ bet, unsigned short* __restrict__ xb) {
    int s = blockIdx.x / GB;
    int bi = blockIdx.x - s * GB;
    int off = bi * 2048 + threadIdx.x * 8;
    if (off >= SLICE) return;
    int node = off >> 4;
    int j0 = off & 15;
    int col0 = s * 16 + j0;
    const float invN = 1.0f / (float)NN;
    short8 hv = *(const short8*)(hb + (size_t)node * 128 + col0);
    short8 xv = *(const short8*)(xb + (size_t)s * SLICE + off);
    short8 o;
    #pragma unroll
    for (int j = 0; j < 8; ++j) {
        int c = col0 + j;
        float mu = stats[c] * invN;
        float var = stats[128 + c] * invN - mu * mu;
        float sc = rsqrtf(var + 1e-5f) * gam[c];
        float val = (bf2f((unsigned short)hv[j]) - mu) * sc + bet[c];
        float r = bf2f((unsigned short)xv[j]) + (val > 0.f ? val : 0.f);
        o[j] = (short)f2bf(r);
    }
    *(short8*)(xb + (size_t)s * SLICE + off) = o;
}

// ---- final classifier: out = x @ lin_W^T + lin_b (N x 47) ----
__global__ __launch_bounds__(256) void k_final(const unsigned short* __restrict__ xb,
                                               const unsigned short* __restrict__ wf,
                                               const float* __restrict__ bias,
                                               float* __restrict__ out) {
    __shared__ unsigned short wsh[6144];
    int tid = threadIdx.x;
    #pragma unroll
    for (int i = 0; i < 3; ++i) {
        int idx = tid + i * 256;
        if (idx < 768) ((int4*)wsh)[idx] = ((const int4*)wf)[idx];
    }
    __syncthreads();

    int wave = tid >> 6, lane = tid & 63, q = lane >> 4, l15 = lane & 15;
    int rowbase = blockIdx.x * 256 + wave * 64;

    f32x4 acc[4][3];
    #pragma unroll
    for (int ct = 0; ct < 3; ++ct) {
        int colg = ct * 16 + l15;
        float bv = (colg < CC) ? bias[colg] : 0.f;
        f32x4 t = {bv, bv, bv, bv};
        #pragma unroll
        for (int rt = 0; rt < 4; ++rt) acc[rt][ct] = t;
    }
    #pragma unroll
    for (int ks = 0; ks < 4; ++ks) {
        int slice = ks * 2 + (q >> 1);
        const unsigned short* sp = xb + (size_t)slice * SLICE + ((q & 1) << 3);
        short8 a[4];
        #pragma unroll
        for (int rt = 0; rt < 4; ++rt) {
            int row = rowbase + rt * 16 + l15;
            if (row < NN) a[rt] = *(const short8*)(sp + ((size_t)row << 4));
            else          a[rt] = short8{0,0,0,0,0,0,0,0};
        }
        #pragma unroll
        for (int ct = 0; ct < 3; ++ct) {
            short8 b = *(const short8*)(wsh + ((ks * 3 + ct) << 9) + (lane << 3));
            #pragma unroll
            for (int rt = 0; rt < 4; ++rt)
                acc[rt][ct] = __builtin_amdgcn_mfma_f32_16x16x32_bf16(a[rt], b, acc[rt][ct], 0, 0, 0);
        }
    }
    #pragma unroll
    for (int ct = 0; ct < 3; ++ct) {
        int colg = ct * 16 + l15;
        if (colg >= CC) continue;
        #pragma unroll
        for (int rt = 0; rt < 4; ++rt) {
            #pragma unroll
            for (int r = 0; r < 4; ++r) {
                int row = rowbase + rt * 16 + (q << 2) + r;
                if (row < NN) out[(size_t)row * CC + colg] = acc[rt][ct][r];
            }
        }
    }
}

extern "C" void kernel_launch(void* const* d_in, const int* in_sizes, int n_in,
                              void* d_out, int out_size, void* d_ws, size_t ws_size,
                              hipStream_t stream) {
    const float* x   = (const float*)d_in[0];
    const int*   ei  = (const int*)d_in[1];
    const float* Wl[3]  = {(const float*)d_in[2],  (const float*)d_in[7],  (const float*)d_in[12]};
    const float* bl[3]  = {(const float*)d_in[3],  (const float*)d_in[8],  (const float*)d_in[13]};
    const float* Wr[3]  = {(const float*)d_in[4],  (const float*)d_in[9],  (const float*)d_in[14]};
    const float* bng[3] = {(const float*)d_in[5],  (const float*)d_in[10], (const float*)d_in[15]};
    const float* bnb[3] = {(const float*)d_in[6],  (const float*)d_in[11], (const float*)d_in[16]};
    const float* linW = (const float*)d_in[17];
    const float* linb = (const float*)d_in[18];

    char* ws = (char*)d_ws;
    unsigned short* xb   = (unsigned short*)(ws + OFF_XB);
    unsigned short* mb   = (unsigned short*)(ws + OFF_MB);
    unsigned short* hb   = (unsigned short*)(ws + OFF_HB);
    int*            bin  = (int*)(ws + OFF_BIN);
    int*            csr  = (int*)(ws + OFF_CSR);
    int*            rp   = (int*)(ws + OFF_RP);
    int*            cur  = (int*)(ws + OFF_CUR);
    int*            base = (int*)(ws + OFF_BASE);
    unsigned short* wfr  = (unsigned short*)(ws + OFF_W);
    float*          st   = (float*)(ws + OFF_ST);
    float*          pbuf = (float*)(ws + OFF_PB);

    hipMemsetAsync(cur, 0, (size_t)NB * 4, stream);
    k_convw<<<408, 256, 0, stream>>>(Wl[0], Wr[0], Wl[1], Wr[1], Wl[2], Wr[2], linW, wfr);
    k_convx<<<8 * GB, 256, 0, stream>>>(x, xb);
    k_bin<<<512, 256, 0, stream>>>(ei, cur, bin);
    k_base<<<1, 512, 0, stream>>>(cur, base, rp);
    k_build<<<NB, 256, 0, stream>>>(cur, base, rp, bin, csr);

    for (int l = 0; l < 3; ++l) {
        hipMemsetAsync(st, 0, 1024, stream);
        k_agg<<<12504, 256, 0, stream>>>(rp, csr, xb, mb);
        k_gemm<<<GB, 256, 0, stream>>>(xb, mb, wfr + (size_t)l * 32768, bl[l], hb, pbuf);
        k_stat2<<<8, 256, 0, stream>>>(pbuf, st);
        k_bn<<<8 * GB, 256, 0, stream>>>(hb, st, bng[l], bnb[l], xb);
    }
    k_final<<<391, 256, 0, stream>>>(xb, wfr + 98304, linb, (float*)d_out);
}

// Round 5
// 525.663 us; speedup vs baseline: 1.4155x; 1.4155x over previous
//
#include <hip/hip_runtime.h>

typedef __attribute__((ext_vector_type(8))) short short8;
typedef __attribute__((ext_vector_type(4))) float f32x4;
typedef __attribute__((ext_vector_type(2))) float f32x2;

constexpr int NN = 100000;
constexpr int EE = 1600000;
constexpr int DD = 128;
constexpr int CC = 47;
constexpr int NB = 391;      // buckets of 256 dst nodes (dst>>8)
constexpr int BSLOT = 5120;  // padded bucket capacity
constexpr int GB = 782;      // gemm grid (128 rows each)

// ---- workspace layout (bytes) ----
constexpr size_t OFF_XB   = 0;           // N*D bf16 running x (row-major)
constexpr size_t OFF_MB   = 25600000;    // N*D bf16 mean agg (row-major)
constexpr size_t OFF_HB   = 51200000;    // N*D bf16 pre-BN h (row-major)
constexpr size_t OFF_XQ   = 76800000;    // N*D fp8 gather shadow of x
constexpr size_t OFF_BIN  = 89600000;    // NB*BSLOT u32 binned packed edges
constexpr size_t OFF_CSR  = 97607680;    // E i32
constexpr size_t OFF_RP   = 104007680;   // N+1 i32 rowptr
constexpr size_t OFF_CUR  = 104407808;   // NB i32 bucket totals
constexpr size_t OFF_BASE = 104409856;   // NB i32 bucket bases
constexpr size_t OFF_W    = 104411904;   // 104448 bf16 frag-ordered weights
constexpr size_t OFF_ST   = 104620800;   // 256 f32 stats (sum, sumsq)
constexpr size_t OFF_PB   = 104621824;   // GB*256 f32 per-block stat partials

static __device__ __forceinline__ float bf2f(unsigned short u) {
    return __uint_as_float(((unsigned)u) << 16);
}
static __device__ __forceinline__ unsigned short f2bf(float f) {
    unsigned u = __float_as_uint(f);
    unsigned r = (u + 0x7fffu + ((u >> 16) & 1u)) >> 16;
    return (unsigned short)r;
}
// pack 8 f32 -> 8 fp8 e4m3 (OCP on gfx950) as uint2
static __device__ __forceinline__ uint2 pack8_fp8(const float* f) {
    int w0 = 0, w1 = 0;
    w0 = __builtin_amdgcn_cvt_pk_fp8_f32(f[0], f[1], w0, false);
    w0 = __builtin_amdgcn_cvt_pk_fp8_f32(f[2], f[3], w0, true);
    w1 = __builtin_amdgcn_cvt_pk_fp8_f32(f[4], f[5], w1, false);
    w1 = __builtin_amdgcn_cvt_pk_fp8_f32(f[6], f[7], w1, true);
    return uint2{(unsigned)w0, (unsigned)w1};
}

// ---- prep: weights -> bf16, MFMA-fragment order ----
__global__ void k_convw(const float* __restrict__ wl1, const float* __restrict__ wr1,
                        const float* __restrict__ wl2, const float* __restrict__ wr2,
                        const float* __restrict__ wl3, const float* __restrict__ wr3,
                        const float* __restrict__ lw, unsigned short* __restrict__ dst) {
    int id = blockIdx.x * 256 + threadIdx.x;
    if (id < 98304) {
        int L = id >> 15;
        int r = id & 32767;
        int mat = r >> 14;
        int t = r & 16383;
        int j = t & 7, lane = (t >> 3) & 63, ct = (t >> 9) & 7, ks = t >> 12;
        int row = ct * 16 + (lane & 15);
        int col = ks * 32 + ((lane >> 4) << 3) + j;
        const float* src = (L == 0) ? (mat ? wr1 : wl1)
                         : (L == 1) ? (mat ? wr2 : wl2)
                                    : (mat ? wr3 : wl3);
        dst[id] = f2bf(src[row * 128 + col]);
    } else if (id < 98304 + 6144) {
        int t = id - 98304;
        int j = t & 7, lane = (t >> 3) & 63, m = t >> 9;
        int ct = m % 3, ks = m / 3;
        int row = ct * 16 + (lane & 15);
        int col = ks * 32 + ((lane >> 4) << 3) + j;
        dst[id] = (row < CC) ? f2bf(lw[row * 128 + col]) : (unsigned short)0;
    }
}

// ---- x (f32) -> xb (bf16) + xq (fp8), row-major, coalesced ----
__global__ void k_convx(const float* __restrict__ x, unsigned short* __restrict__ xb,
                        unsigned char* __restrict__ xq) {
    int i = (blockIdx.x * 256 + threadIdx.x) * 8;
    if (i >= NN * DD) return;
    float4 v1 = *(const float4*)(x + i);
    float4 v2 = *(const float4*)(x + i + 4);
    float f[8] = {v1.x, v1.y, v1.z, v1.w, v2.x, v2.y, v2.z, v2.w};
    short8 o;
    #pragma unroll
    for (int j = 0; j < 8; ++j) o[j] = (short)f2bf(f[j]);
    *(short8*)(xb + i) = o;
    *(uint2*)(xq + i) = pack8_fp8(f);
}

// ---- pass A: bin edges by dst>>8 ----
__global__ __launch_bounds__(256) void k_bin(const int* __restrict__ ei,
                                             int* __restrict__ cur, int* __restrict__ bin) {
    __shared__ int cnt[NB];
    int t = threadIdx.x;
    for (int b = t; b < NB; b += 256) cnt[b] = 0;
    __syncthreads();
    int start = blockIdx.x * 3125;
    for (int i = t; i < 3125; i += 256) {
        int d = ei[EE + start + i];
        atomicAdd(&cnt[d >> 8], 1);
    }
    __syncthreads();
    int c[2], b0[2];
    #pragma unroll
    for (int k = 0; k < 2; ++k) {
        int b = t + k * 256;
        if (b < NB) { c[k] = cnt[b]; b0[k] = (c[k] > 0) ? atomicAdd(&cur[b], c[k]) : 0; }
    }
    __syncthreads();
    #pragma unroll
    for (int k = 0; k < 2; ++k) {
        int b = t + k * 256;
        if (b < NB) cnt[b] = b0[k];
    }
    __syncthreads();
    for (int i = t; i < 3125; i += 256) {
        int s = ei[start + i];
        int d = ei[EE + start + i];
        int b = d >> 8;
        int p = atomicAdd(&cnt[b], 1);
        if (p < BSLOT) bin[b * BSLOT + p] = (s << 8) | (d & 255);
    }
}

__global__ void k_base(const int* __restrict__ cur, int* __restrict__ base, int* __restrict__ rp) {
    __shared__ int sd[512];
    int t = threadIdx.x;
    int v0 = (t < NB) ? cur[t] : 0;
    sd[t] = v0;
    __syncthreads();
    for (int off = 1; off < 512; off <<= 1) {
        int v = (t >= off) ? sd[t - off] : 0;
        __syncthreads();
        sd[t] += v;
        __syncthreads();
    }
    if (t < NB) base[t] = sd[t] - v0;
    if (t == NB - 1) rp[NN] = sd[t];
}

__global__ __launch_bounds__(256) void k_build(const int* __restrict__ cur, const int* __restrict__ base,
                                               int* __restrict__ rp, const int* __restrict__ bin,
                                               int* __restrict__ csr) {
    __shared__ int lcnt[256], lsc[256], lrun[256];
    int b = blockIdx.x, t = threadIdx.x;
    int n0 = b << 8;
    int nodes = NN - n0; if (nodes > 256) nodes = 256;
    int tot = cur[b]; if (tot > BSLOT) tot = BSLOT;
    int bb = base[b];
    lcnt[t] = 0;
    __syncthreads();
    const int* bsrc = bin + b * BSLOT;
    for (int i = t; i < tot; i += 256) atomicAdd(&lcnt[bsrc[i] & 255], 1);
    __syncthreads();
    int c = lcnt[t];
    lsc[t] = c;
    __syncthreads();
    for (int off = 1; off < 256; off <<= 1) {
        int v = (t >= off) ? lsc[t - off] : 0;
        __syncthreads();
        lsc[t] += v;
        __syncthreads();
    }
    int excl = lsc[t] - c;
    if (t < nodes) rp[n0 + t] = bb + excl;
    lrun[t] = bb + excl;
    __syncthreads();
    for (int i = t; i < tot; i += 256) {
        int v = bsrc[i];
        int p = atomicAdd(&lrun[v & 255], 1);
        csr[p] = v >> 8;
    }
}

// ---- mean aggregation from fp8 shadow: wave per node, 4 edges in flight ----
// 16 lanes per edge x 8B = 128B full-line gather per edge.
// cb is the ELEMENT index (fp8 elem == bf16 elem position), used for both xq and mb.
__global__ __launch_bounds__(256) void k_agg(const int* __restrict__ rp, const int* __restrict__ csr,
                                             const unsigned char* __restrict__ xq,
                                             unsigned short* __restrict__ mb) {
    int node = blockIdx.x * 4 + (threadIdx.x >> 6);
    if (node >= NN) return;
    int lane = threadIdx.x & 63;
    int g = lane >> 4;            // edge sub-slot 0..3
    int cb = (lane & 15) << 3;    // 8-element column window
    int s0 = rp[node], s1 = rp[node + 1];
    float acc[8] = {0.f,0.f,0.f,0.f,0.f,0.f,0.f,0.f};
    int e = s0 + g;
    int nx = (e < s1) ? csr[e] : 0;
    for (; e < s1; e += 4) {
        int cur = nx;
        if (e + 4 < s1) nx = csr[e + 4];
        uint2 v = *(const uint2*)(xq + (size_t)cur * 128 + cb);
        f32x2 p0 = __builtin_amdgcn_cvt_pk_f32_fp8(v.x, false);
        f32x2 p1 = __builtin_amdgcn_cvt_pk_f32_fp8(v.x, true);
        f32x2 p2 = __builtin_amdgcn_cvt_pk_f32_fp8(v.y, false);
        f32x2 p3 = __builtin_amdgcn_cvt_pk_f32_fp8(v.y, true);
        acc[0] += p0[0]; acc[1] += p0[1];
        acc[2] += p1[0]; acc[3] += p1[1];
        acc[4] += p2[0]; acc[5] += p2[1];
        acc[6] += p3[0]; acc[7] += p3[1];
    }
    #pragma unroll
    for (int j = 0; j < 8; ++j) {
        acc[j] += __shfl_xor(acc[j], 16);
        acc[j] += __shfl_xor(acc[j], 32);
    }
    if (g == 0) {
        int deg = s1 - s0;
        float inv = 1.0f / (float)(deg > 1 ? deg : 1);
        short8 o;
        #pragma unroll
        for (int j = 0; j < 8; ++j) o[j] = (short)f2bf(acc[j] * inv);
        *(short8*)(mb + (size_t)node * 128 + cb) = o;   // FIX: element index, not cb<<1
    }
}

// ---- fused SAGE GEMM: h = x@Wl^T + bl + mean@Wr^T; per-block stat partials ----
__global__ __launch_bounds__(256, 4) void k_gemm(const unsigned short* __restrict__ xb,
                                                 const unsigned short* __restrict__ mb,
                                                 const unsigned short* __restrict__ wf,
                                                 const float* __restrict__ bias,
                                                 unsigned short* __restrict__ hb,
                                                 float* __restrict__ pbuf) {
    __shared__ unsigned short wsh[16384];   // 32 KB: one matrix at a time
    __shared__ float rbuf[1024];            // cross-wave stat reduce
    int tid = threadIdx.x;
    int wave = tid >> 6, lane = tid & 63, q = lane >> 4, l15 = lane & 15;
    int rowbase = blockIdx.x * 128 + wave * 32;

    f32x4 acc[2][8];
    #pragma unroll
    for (int ct = 0; ct < 8; ++ct) {
        float bv = bias[ct * 16 + l15];
        f32x4 t = {bv, bv, bv, bv};
        acc[0][ct] = t; acc[1][ct] = t;
    }

    #pragma unroll
    for (int mat = 0; mat < 2; ++mat) {
        const unsigned short* src = mat ? mb : xb;
        const int4* wsrc = (const int4*)(wf + (mat << 14));
        if (mat) __syncthreads();           // drain mat-0 LDS reads before overwrite
        #pragma unroll
        for (int i = 0; i < 8; ++i)
            ((int4*)wsh)[tid + i * 256] = wsrc[tid + i * 256];
        __syncthreads();
        #pragma unroll
        for (int ks = 0; ks < 4; ++ks) {
            short8 a[2];
            #pragma unroll
            for (int rt = 0; rt < 2; ++rt) {
                int row = rowbase + rt * 16 + l15;
                if (row < NN) a[rt] = *(const short8*)(src + (size_t)row * 128 + ks * 32 + (q << 3));
                else          a[rt] = short8{0,0,0,0,0,0,0,0};
            }
            #pragma unroll
            for (int ct = 0; ct < 8; ++ct) {
                short8 b = *(const short8*)(wsh + ((ks * 8 + ct) << 9) + (lane << 3));
                acc[0][ct] = __builtin_amdgcn_mfma_f32_16x16x32_bf16(a[0], b, acc[0][ct], 0, 0, 0);
                acc[1][ct] = __builtin_amdgcn_mfma_f32_16x16x32_bf16(a[1], b, acc[1][ct], 0, 0, 0);
            }
        }
    }

    // epilogue: bf16 store + per-block column stat partials (no global atomics)
    #pragma unroll
    for (int ct = 0; ct < 8; ++ct) {
        int colg = ct * 16 + l15;
        float sv = 0.f, qv = 0.f;
        #pragma unroll
        for (int rt = 0; rt < 2; ++rt) {
            #pragma unroll
            for (int r = 0; r < 4; ++r) {
                int row = rowbase + rt * 16 + (q << 2) + r;
                if (row < NN) {
                    float v = acc[rt][ct][r];
                    hb[(size_t)row * 128 + colg] = f2bf(v);
                    sv += v; qv += v * v;
                }
            }
        }
        sv += __shfl_xor(sv, 16); sv += __shfl_xor(sv, 32);
        qv += __shfl_xor(qv, 16); qv += __shfl_xor(qv, 32);
        if (q == 0) {
            rbuf[wave * 256 + colg] = sv;
            rbuf[wave * 256 + 128 + colg] = qv;
        }
    }
    __syncthreads();
    if (tid < 256) {
        float v = rbuf[tid] + rbuf[256 + tid] + rbuf[512 + tid] + rbuf[768 + tid];
        pbuf[(size_t)blockIdx.x * 256 + tid] = v;
    }
}

// ---- reduce stat partials ----
__global__ void k_stat2(const float* __restrict__ pbuf, float* __restrict__ st) {
    int b = blockIdx.x, t = threadIdx.x;   // 8 blocks x 256
    int r0 = b * 98;
    int r1 = r0 + 98; if (r1 > GB) r1 = GB;
    float s = 0.f;
    for (int r = r0; r < r1; ++r) s += pbuf[(size_t)r * 256 + t];
    atomicAdd(&st[t], s);
}

// ---- BatchNorm + ReLU + residual; emits bf16 x and fp8 shadow ----
__global__ void k_bn(const unsigned short* __restrict__ hb,
                     const float* __restrict__ stats, const float* __restrict__ gam,
                     const float* __restrict__ bet, unsigned short* __restrict__ xb,
                     unsigned char* __restrict__ xq) {
    int i = (blockIdx.x * 256 + threadIdx.x) * 8;
    if (i >= NN * DD) return;
    int col = i & 127;
    const float invN = 1.0f / (float)NN;
    short8 hv = *(const short8*)(hb + i);
    short8 xv = *(const short8*)(xb + i);
    short8 o;
    float f[8];
    #pragma unroll
    for (int j = 0; j < 8; ++j) {
        int c = col + j;
        float mu = stats[c] * invN;
        float var = stats[128 + c] * invN - mu * mu;
        float sc = rsqrtf(var + 1e-5f) * gam[c];
        float val = (bf2f((unsigned short)hv[j]) - mu) * sc + bet[c];
        float r = bf2f((unsigned short)xv[j]) + (val > 0.f ? val : 0.f);
        f[j] = r;
        o[j] = (short)f2bf(r);
    }
    *(short8*)(xb + i) = o;
    *(uint2*)(xq + i) = pack8_fp8(f);
}

// ---- final classifier: out = x @ lin_W^T + lin_b (N x 47) ----
__global__ __launch_bounds__(256) void k_final(const unsigned short* __restrict__ xb,
                                               const unsigned short* __restrict__ wf,
                                               const float* __restrict__ bias,
                                               float* __restrict__ out) {
    __shared__ unsigned short wsh[6144];
    int tid = threadIdx.x;
    #pragma unroll
    for (int i = 0; i < 3; ++i) {
        int idx = tid + i * 256;
        if (idx < 768) ((int4*)wsh)[idx] = ((const int4*)wf)[idx];
    }
    __syncthreads();

    int wave = tid >> 6, lane = tid & 63, q = lane >> 4, l15 = lane & 15;
    int rowbase = blockIdx.x * 256 + wave * 64;

    f32x4 acc[4][3];
    #pragma unroll
    for (int ct = 0; ct < 3; ++ct) {
        int colg = ct * 16 + l15;
        float bv = (colg < CC) ? bias[colg] : 0.f;
        f32x4 t = {bv, bv, bv, bv};
        #pragma unroll
        for (int rt = 0; rt < 4; ++rt) acc[rt][ct] = t;
    }
    #pragma unroll
    for (int ks = 0; ks < 4; ++ks) {
        short8 a[4];
        #pragma unroll
        for (int rt = 0; rt < 4; ++rt) {
            int row = rowbase + rt * 16 + l15;
            if (row < NN) a[rt] = *(const short8*)(xb + (size_t)row * 128 + ks * 32 + (q << 3));
            else          a[rt] = short8{0,0,0,0,0,0,0,0};
        }
        #pragma unroll
        for (int ct = 0; ct < 3; ++ct) {
            short8 b = *(const short8*)(wsh + ((ks * 3 + ct) << 9) + (lane << 3));
            #pragma unroll
            for (int rt = 0; rt < 4; ++rt)
                acc[rt][ct] = __builtin_amdgcn_mfma_f32_16x16x32_bf16(a[rt], b, acc[rt][ct], 0, 0, 0);
        }
    }
    #pragma unroll
    for (int ct = 0; ct < 3; ++ct) {
        int colg = ct * 16 + l15;
        if (colg >= CC) continue;
        #pragma unroll
        for (int rt = 0; rt < 4; ++rt) {
            #pragma unroll
            for (int r = 0; r < 4; ++r) {
                int row = rowbase + rt * 16 + (q << 2) + r;
                if (row < NN) out[(size_t)row * CC + colg] = acc[rt][ct][r];
            }
        }
    }
}

extern "C" void kernel_launch(void* const* d_in, const int* in_sizes, int n_in,
                              void* d_out, int out_size, void* d_ws, size_t ws_size,
                              hipStream_t stream) {
    const float* x   = (const float*)d_in[0];
    const int*   ei  = (const int*)d_in[1];
    const float* Wl[3]  = {(const float*)d_in[2],  (const float*)d_in[7],  (const float*)d_in[12]};
    const float* bl[3]  = {(const float*)d_in[3],  (const float*)d_in[8],  (const float*)d_in[13]};
    const float* Wr[3]  = {(const float*)d_in[4],  (const float*)d_in[9],  (const float*)d_in[14]};
    const float* bng[3] = {(const float*)d_in[5],  (const float*)d_in[10], (const float*)d_in[15]};
    const float* bnb[3] = {(const float*)d_in[6],  (const float*)d_in[11], (const float*)d_in[16]};
    const float* linW = (const float*)d_in[17];
    const float* linb = (const float*)d_in[18];

    char* ws = (char*)d_ws;
    unsigned short* xb   = (unsigned short*)(ws + OFF_XB);
    unsigned short* mb   = (unsigned short*)(ws + OFF_MB);
    unsigned short* hb   = (unsigned short*)(ws + OFF_HB);
    unsigned char*  xq   = (unsigned char*)(ws + OFF_XQ);
    int*            bin  = (int*)(ws + OFF_BIN);
    int*            csr  = (int*)(ws + OFF_CSR);
    int*            rp   = (int*)(ws + OFF_RP);
    int*            cur  = (int*)(ws + OFF_CUR);
    int*            base = (int*)(ws + OFF_BASE);
    unsigned short* wfr  = (unsigned short*)(ws + OFF_W);
    float*          st   = (float*)(ws + OFF_ST);
    float*          pbuf = (float*)(ws + OFF_PB);

    hipMemsetAsync(cur, 0, (size_t)NB * 4, stream);
    k_convw<<<408, 256, 0, stream>>>(Wl[0], Wr[0], Wl[1], Wr[1], Wl[2], Wr[2], linW, wfr);
    k_convx<<<6250, 256, 0, stream>>>(x, xb, xq);
    k_bin<<<512, 256, 0, stream>>>(ei, cur, bin);
    k_base<<<1, 512, 0, stream>>>(cur, base, rp);
    k_build<<<NB, 256, 0, stream>>>(cur, base, rp, bin, csr);

    for (int l = 0; l < 3; ++l) {
        hipMemsetAsync(st, 0, 1024, stream);
        k_agg<<<25000, 256, 0, stream>>>(rp, csr, xq, mb);
        k_gemm<<<GB, 256, 0, stream>>>(xb, mb, wfr + (size_t)l * 32768, bl[l], hb, pbuf);
        k_stat2<<<8, 256, 0, stream>>>(pbuf, st);
        k_bn<<<6250, 256, 0, stream>>>(hb, st, bng[l], bnb[l], xb, xq);
    }
    k_final<<<391, 256, 0, stream>>>(xb, wfr + 98304, linb, (float*)d_out);
}